// Round 8
// baseline (226.794 us; speedup 1.0000x reference)
//
#include <hip/hip_runtime.h>
#include <hip/hip_fp16.h>

// GCN VGAE encoder:
//   h  = relu((A @ x) @ W1 + b1)          [associativity: A(xW) == (Ax)W]
//   mu = (A @ h) @ Wmu + bmu ; lv = (A @ h) @ Wlv + blv
// A = D^-1/2 (Adj + I) D^-1/2, deg on dst side. dinv folded into tables:
//   xs[s]=dinv_s*x[s]; hs[i]=dinv_i*relu(...); y_i = dinv_i*(sum_e xs[src]+xs[i])
//
// R19: kill redundant traversals in the two heavy build kernels (they are
// latency-bound per R18, so a second full pass costs a traversal, not bytes):
//  * bucket_scatter: phase 1 stashes packed payload (16KB) + bucket ids
//    (4KB, u8x4) in LDS; phase 3 is LDS->LDS (no 12.8MB global re-read).
//    LDS ~42KB -> co-residency preserved.
//  * bucket_build: histogram pass stashes the tmp window (<=10240 ints,
//    41KB) in LDS; sort pass reads LDS (no 6.4MB re-read). ~87KB LDS,
//    1 block/CU as before. Global fallback kept for len>STAGE_CAP.
// Everything else byte-identical to R18 (224.4us). Build lever history:
// bytes 0, boundaries ~0.6us, global atomics dead (235ns/addr), grid.sync
// dead (~130us), write granularity +12us, concurrency +5us. Aggs at the
// 7-config random-gather plateau. Pre-commit: >=220us -> roofline.

#define BKT_SHIFT 9
#define BKT_NODES 512
#define CHUNK 4096
#define STAGE_CAP 10240

typedef __attribute__((ext_vector_type(8))) _Float16 half8;
typedef __attribute__((ext_vector_type(4))) float float4v;
typedef __attribute__((ext_vector_type(4))) unsigned uint4v;

__device__ __forceinline__ int imin(int a, int b) { return a < b ? a : b; }
__device__ __forceinline__ int imax(int a, int b) { return a > b ? a : b; }
__device__ __forceinline__ unsigned h2u(__half2 v) {
  union { __half2 h; unsigned u; } c; c.h = v; return c.u;
}
__device__ __forceinline__ __half2 u2h(unsigned x) {
  union { unsigned u; __half2 h; } c; c.u = x; return c.h;
}

// ---------------- A0: per-chunk bucket histogram (512 thr, 391 blocks) -----
__global__ __launch_bounds__(512) void bucket_count(const int* __restrict__ dst,
                                                    int* __restrict__ cnt,
                                                    int E, int nbk, int nblk) {
  __shared__ int hist[2][256];
  const int t = threadIdx.x;
  hist[t >> 8][t & 255] = 0;
  __syncthreads();
  const int h = (t >> 8) & 1;
  const int base = blockIdx.x * CHUNK;
  const int end = imin(base + CHUNK, E);
  for (int e = base + t * 4; e < end; e += 2048) {
    if (e + 3 < end) {
      const int4 d4 = *(const int4*)(dst + e);
      atomicAdd(&hist[h][d4.x >> BKT_SHIFT], 1);
      atomicAdd(&hist[h][d4.y >> BKT_SHIFT], 1);
      atomicAdd(&hist[h][d4.z >> BKT_SHIFT], 1);
      atomicAdd(&hist[h][d4.w >> BKT_SHIFT], 1);
    } else {
      for (int k = e; k < end; ++k) atomicAdd(&hist[h][dst[k] >> BKT_SHIFT], 1);
    }
  }
  __syncthreads();
  if (t < nbk) cnt[t * nblk + blockIdx.x] = hist[0][t] + hist[1][t];
}

// ---------------- A1: per-bucket row scan (in place), nblk <= 512 ----------
__global__ __launch_bounds__(256) void scan_rows(int* __restrict__ cnt,
                                                 int* __restrict__ rowsum,
                                                 int nbk, int nblk) {
  __shared__ int red[256];
  const int b = blockIdx.x;
  const int t = threadIdx.x;
  const int rbase = b * nblk;
  const int i0 = 2 * t, i1 = 2 * t + 1;
  const int v0 = (i0 < nblk) ? cnt[rbase + i0] : 0;
  const int v1 = (i1 < nblk) ? cnt[rbase + i1] : 0;
  const int run = v0 + v1;
  red[t] = run;
  __syncthreads();
  for (int off = 1; off < 256; off <<= 1) {
    const int u = (t >= off) ? red[t - off] : 0;
    __syncthreads();
    red[t] += u;
    __syncthreads();
  }
  const int acc = red[t] - run;
  if (t == 255) rowsum[b] = red[255];
  if (i0 < nblk) cnt[rbase + i0] = acc;
  if (i1 < nblk) cnt[rbase + i1] = acc + v0;
}

// ---------------- A2: LDS-staged scatter, single global edge pass ----------
// tmp entry packed: (src << 9) | (dst & 511)  [src < 2^17 for N=100k].
// Phase 1 loads edges ONCE, stashing payload + bucket id in LDS; phase 3 is
// LDS->LDS; phase 4 streams runs out line-granular.
__global__ __launch_bounds__(512) void bucket_scatter(const int* __restrict__ src,
                                                      const int* __restrict__ dst,
                                                      const int* __restrict__ cnt,
                                                      const int* __restrict__ rowsum,
                                                      int* __restrict__ tmp,
                                                      int E, int nbk, int nblk) {
  __shared__ int hist[2][256];
  __shared__ int lofs[256];
  __shared__ int gofs[256];
  __shared__ int cur[256];
  __shared__ int red[256];
  __shared__ int pay[CHUNK];        // packed payloads, chunk order
  __shared__ int bktw[CHUNK / 4];   // bucket ids, 4x u8 packed
  __shared__ int stage[CHUNK];      // bucket-sorted payloads
  const int t = threadIdx.x;
  const int c = blockIdx.x;
  hist[t >> 8][t & 255] = 0;
  __syncthreads();
  const int h = (t >> 8) & 1;
  const int base = c * CHUNK;
  const int end = imin(base + CHUNK, E);
  const int len = end - base;
  // phase 1: single global pass -> hist + LDS stash
  for (int e = base + t * 4; e < end; e += 2048) {
    const int li = e - base;
    if (e + 3 < end) {
      const int4 s4 = *(const int4*)(src + e);
      const int4 d4 = *(const int4*)(dst + e);
      const int b0 = d4.x >> BKT_SHIFT, b1 = d4.y >> BKT_SHIFT;
      const int b2 = d4.z >> BKT_SHIFT, b3 = d4.w >> BKT_SHIFT;
      atomicAdd(&hist[h][b0], 1);
      atomicAdd(&hist[h][b1], 1);
      atomicAdd(&hist[h][b2], 1);
      atomicAdd(&hist[h][b3], 1);
      pay[li] = (s4.x << 9) | (d4.x & 511);
      pay[li + 1] = (s4.y << 9) | (d4.y & 511);
      pay[li + 2] = (s4.z << 9) | (d4.z & 511);
      pay[li + 3] = (s4.w << 9) | (d4.w & 511);
      bktw[li >> 2] = b0 | (b1 << 8) | (b2 << 16) | (b3 << 24);
    } else {
      int bw = 0;
      for (int k = e; k < end; ++k) {
        const int d = dst[k];
        const int b = d >> BKT_SHIFT;
        atomicAdd(&hist[h][b], 1);
        pay[k - base] = (src[k] << 9) | (d & 511);
        bw |= b << (((k - base) & 3) * 8);
      }
      if (e < end) bktw[li >> 2] = bw;
    }
  }
  __syncthreads();
  // phase 2a: local exclusive scan of bucket counts
  int tot = 0;
  if (t < 256) {
    tot = hist[0][t] + hist[1][t];
    red[t] = tot;
  }
  __syncthreads();
  for (int off = 1; off < 256; off <<= 1) {
    int u = 0;
    if (t < 256 && t >= off) u = red[t - off];
    __syncthreads();
    if (t < 256) red[t] += u;
    __syncthreads();
  }
  if (t < 256) {
    lofs[t] = red[t] - tot;
    cur[t] = red[t] - tot;
  }
  __syncthreads();
  // phase 2b: global offsets = rowbase (local scan of rowsum) + cnt prefix
  int rv = 0;
  if (t < 256) {
    rv = (t < nbk) ? rowsum[t] : 0;
    red[t] = rv;
  }
  __syncthreads();
  for (int off = 1; off < 256; off <<= 1) {
    int u = 0;
    if (t < 256 && t >= off) u = red[t - off];
    __syncthreads();
    if (t < 256) red[t] += u;
    __syncthreads();
  }
  if (t < nbk) gofs[t] = (red[t] - rv) + cnt[t * nblk + c];
  __syncthreads();
  // phase 3: LDS -> LDS bucket sort
  for (int li = t; li < len; li += 512) {
    const int b = (bktw[li >> 2] >> ((li & 3) * 8)) & 255;
    const int pos = atomicAdd(&cur[b], 1);
    stage[pos] = pay[li];
  }
  __syncthreads();
  // phase 4: stream each bucket's run out (dense runs combine in L2)
  const int wv = t >> 6, lane = t & 63;
  for (int b = wv; b < nbk; b += 8) {
    const int rl = hist[0][b] + hist[1][b];
    const int lo = lofs[b];
    const int go = gofs[b];
    for (int k = lane; k < rl; k += 64) tmp[go + k] = stage[lo + k];
  }
}

// ---------------- B: per-bucket CSR build, single tmp pass -----------------
// 1024 threads/block, 196 blocks. Histogram pass stashes the window in LDS;
// sort pass reads LDS. Coalesced pairs stream-out. Fallback (len>STAGE_CAP)
// keeps the two-pass global path.
__global__ __launch_bounds__(1024) void bucket_build(const int* __restrict__ tmp,
                                                     const int* __restrict__ rowsum,
                                                     int* __restrict__ row_ptr,
                                                     float* __restrict__ dinv,
                                                     int* __restrict__ pairs,
                                                     int n, int nbk, int E) {
  __shared__ int hist[BKT_NODES];
  __shared__ int scn[BKT_NODES];
  __shared__ int red[256];
  __shared__ int win[STAGE_CAP];    // stashed window (chunk-run order)
  __shared__ int stage[STAGE_CAP];  // node-sorted srcs
  __shared__ int s_sh;
  const int b = blockIdx.x;
  const int t = threadIdx.x;
  const int node0 = b << BKT_SHIFT;
  int v0 = 0;
  if (t < 256) {
    v0 = (t < nbk) ? rowsum[t] : 0;
    red[t] = v0;
  }
  if (t < BKT_NODES) hist[t] = 0;
  __syncthreads();
  for (int off = 1; off < 256; off <<= 1) {
    int u = 0;
    if (t < 256 && t >= off) u = red[t - off];
    __syncthreads();
    if (t < 256) red[t] += u;
    __syncthreads();
  }
  if (t == 0) s_sh = red[b] - rowsum[b];
  __syncthreads();
  const int s = s_sh;
  const int e = s + rowsum[b];
  const int len = e - s;
  const bool staged = (len <= STAGE_CAP);
  if (staged) {
    for (int k = s + t; k < e; k += 1024) {
      const int w = tmp[k];
      win[k - s] = w;
      atomicAdd(&hist[w & 511], 1);
    }
  } else {
    for (int k = s + t; k < e; k += 1024) atomicAdd(&hist[tmp[k] & 511], 1);
  }
  __syncthreads();
  int v = 0;
  if (t < BKT_NODES) {
    v = hist[t];
    scn[t] = v;
  }
  __syncthreads();
  for (int off = 1; off < BKT_NODES; off <<= 1) {
    int u = 0;
    if (t < BKT_NODES && t >= off) u = scn[t - off];
    __syncthreads();
    if (t < BKT_NODES) scn[t] += u;
    __syncthreads();
  }
  if (t < BKT_NODES) {
    const int lexcl = scn[t] - v;
    const int node = node0 + t;
    if (node < n) {
      row_ptr[node] = s + lexcl;
      dinv[node] = rsqrtf(1.0f + (float)v);  // deg includes self-loop
    }
    if (b == nbk - 1 && t == 0) row_ptr[n] = E;
    hist[t] = staged ? lexcl : (s + lexcl);  // cursor (local/global)
  }
  __syncthreads();
  if (staged) {
    for (int k = t; k < len; k += 1024) {
      const int w = win[k];
      const int pos = atomicAdd(&hist[w & 511], 1);
      stage[pos] = w >> 9;
    }
    __syncthreads();
    for (int k = t; k < len; k += 1024) pairs[s + k] = stage[k];
  } else {
    for (int k = s + t; k < e; k += 1024) {
      const int w = tmp[k];
      const int pos = atomicAdd(&hist[w & 511], 1);
      pairs[pos] = w >> 9;
    }
  }
}

// ---------------- table prep (standalone, chip-filling: R11 shape) ---------
__global__ __launch_bounds__(256) void cast_scale(const float* __restrict__ x,
                                                  const float* __restrict__ dinv,
                                                  __half* __restrict__ xs,
                                                  __half* __restrict__ hs,
                                                  int n4, int nrow) {
  int i = blockIdx.x * blockDim.x + threadIdx.x;
  if (i < n4) {
    float4 v = ((const float4*)x)[i];
    float d = dinv[i >> 4];
    __half2* o = (__half2*)(xs + (size_t)i * 4);
    o[0] = __floats2half2_rn(d * v.x, d * v.y);
    o[1] = __floats2half2_rn(d * v.z, d * v.w);
  } else if (i < n4 + 32) {
    int j = i - n4;
    if (j < 16)
      ((float2*)(xs + (size_t)nrow * 64))[j] = make_float2(0.f, 0.f);
    else
      ((float2*)(hs + (size_t)nrow * 64))[j - 16] = make_float2(0.f, 0.f);
  }
}

// ---------------- aggregation + fused dense via MFMA (R8/R11 config) -------
// Wave handles 16 rows (4 groups of 4 rows interleaved). Per row: 8 edge
// slots (lane=8g+q, 16B of 8 halves/lane), packed-half2 accumulate; 4 rows'
// pairs-prefetch + gather chains run concurrently. One xor-32 fold (slots
// 8->4), self-term on g==0, di-scale, store to wave-private LDS A-tile
// ylds[row][(g&3)*64 + 8q+c] (K'=256; last 4-slot reduction rides the MFMA
// K-dim, B = W replicated over the 4 slots). 8 k-steps x 4 n-tiles of
// mfma_f32_16x16x32_f16, bias in C-init.
// A layout: A[m=lane&15][k=(lane>>4)*8+j]; C/D: col=lane&15, row=quad*4+reg.

#define YSTRIDE 264  // 256 + 8 halves pad

__global__ __launch_bounds__(256, 4) void agg_layer1(const __half* __restrict__ xs,
                                                     const int* __restrict__ pairs,
                                                     const int* __restrict__ row_ptr,
                                                     const float* __restrict__ W1,
                                                     const float* __restrict__ b1,
                                                     __half* __restrict__ hs, int n) {
  __shared__ _Float16 ylds_all[4][16 * YSTRIDE];
  __shared__ float dilds_all[4][16];
  const int wv = threadIdx.x >> 6;
  _Float16* ylds = ylds_all[wv];
  float* dilds = dilds_all[wv];
  const int lane = threadIdx.x & 63;
  const int g = lane >> 3, q = lane & 7;
  const int quad = lane >> 4, col = lane & 15;

  // B-fragments: k = s2*32 + quad*8 + jj; feature = k & 63 -> sW = s2 & 1.
  half8 bfrag[2][4];
#pragma unroll
  for (int s = 0; s < 2; ++s)
#pragma unroll
    for (int t = 0; t < 4; ++t)
#pragma unroll
      for (int jj = 0; jj < 8; ++jj)
        bfrag[s][t][jj] = (_Float16)W1[(s * 32 + quad * 8 + jj) * 64 + t * 16 + col];
  float bias[4];
#pragma unroll
  for (int t = 0; t < 4; ++t) bias[t] = b1[t * 16 + col];

  const int ntiles = (n + 15) >> 4;
  for (int tile = blockIdx.x * 4 + wv; tile < ntiles; tile += gridDim.x * 4) {
    const int row0 = tile << 4;
#pragma unroll 1
    for (int rg = 0; rg < 4; ++rg) {  // 4 rows interleaved per group
      int start[4], end[4], idx[4];
      __half2 acc[4][4];
      int maxdeg = 0;
#pragma unroll
      for (int j = 0; j < 4; ++j) {
        const int i = row0 + rg * 4 + j;
        start[j] = 0; end[j] = 0;
        if (i < n) { start[j] = row_ptr[i]; end[j] = row_ptr[i + 1]; }
        maxdeg = imax(maxdeg, end[j] - start[j]);
#pragma unroll
        for (int k = 0; k < 4; ++k) acc[j][k] = u2h(0u);
        idx[j] = (start[j] + g < end[j]) ? pairs[start[j] + g] : n;
      }
      const int iters = (maxdeg + 7) >> 3;
#pragma unroll 1
      for (int it = 0; it < iters; ++it) {
        int nidx[4];
#pragma unroll
        for (int j = 0; j < 4; ++j) {
          const int ofs2 = start[j] + (it + 1) * 8 + g;
          nidx[j] = (ofs2 < end[j]) ? pairs[ofs2] : n;
        }
#pragma unroll
        for (int j = 0; j < 4; ++j) {
          const float4 rr = *(const float4*)(xs + (size_t)idx[j] * 64 + q * 8);
          const __half2* hp = (const __half2*)&rr;
#pragma unroll
          for (int k = 0; k < 4; ++k) acc[j][k] = __hadd2(acc[j][k], hp[k]);
        }
#pragma unroll
        for (int j = 0; j < 4; ++j) idx[j] = nidx[j];
      }
#pragma unroll
      for (int j = 0; j < 4; ++j) {
        const int i = row0 + rg * 4 + j;
        // self term (once, on g==0 lanes)
        if (g == 0 && i < n) {
          const float4 sr = *(const float4*)(xs + (size_t)i * 64 + q * 8);
          const __half2* hp = (const __half2*)&sr;
#pragma unroll
          for (int k = 0; k < 4; ++k) acc[j][k] = __hadd2(acc[j][k], hp[k]);
        }
        // fold slots g and g^4 (lane xor 32)
#pragma unroll
        for (int k = 0; k < 4; ++k) {
          unsigned u = __shfl_xor(h2u(acc[j][k]), 32);
          acc[j][k] = __hadd2(acc[j][k], u2h(u));
        }
        const float di = rsqrtf((float)(1 + end[j] - start[j]));
        const __half hdi = __float2half(di);
        const __half2 di2 = __halves2half2(hdi, hdi);
        uint4v st;
        st.x = h2u(__hmul2(di2, acc[j][0]));
        st.y = h2u(__hmul2(di2, acc[j][1]));
        st.z = h2u(__hmul2(di2, acc[j][2]));
        st.w = h2u(__hmul2(di2, acc[j][3]));
        *(uint4v*)(ylds + (rg * 4 + j) * YSTRIDE + (g & 3) * 64 + q * 8) = st;
        if (lane == 0) dilds[rg * 4 + j] = di;
      }
    }
    // MFMA: D = A(16x256) * B'(256x64) + bias
    float4v acc[4];
#pragma unroll
    for (int t = 0; t < 4; ++t) acc[t] = (float4v){bias[t], bias[t], bias[t], bias[t]};
#pragma unroll
    for (int s2 = 0; s2 < 8; ++s2) {
      half8 af = *(half8*)(ylds + col * YSTRIDE + s2 * 32 + quad * 8);
      const int sW = s2 & 1;
#pragma unroll
      for (int t = 0; t < 4; ++t)
        acc[t] = __builtin_amdgcn_mfma_f32_16x16x32_f16(af, bfrag[sW][t], acc[t], 0, 0, 0);
    }
    const float4 dis = *(const float4*)(dilds + quad * 4);
    const float dd[4] = {dis.x, dis.y, dis.z, dis.w};
#pragma unroll
    for (int t = 0; t < 4; ++t)
#pragma unroll
      for (int reg = 0; reg < 4; ++reg) {
        const int row = row0 + quad * 4 + reg;
        if (row < n)
          hs[(size_t)row * 64 + t * 16 + col] =
              __float2half(dd[reg] * fmaxf(acc[t][reg], 0.f));
      }
  }
}

// Layer 2: same structure; B' = [Wmu | Wlv] (64 cols), fp32 outputs.
__global__ __launch_bounds__(256, 4) void agg_layer2(const __half* __restrict__ hsin,
                                                     const int* __restrict__ pairs,
                                                     const int* __restrict__ row_ptr,
                                                     const float* __restrict__ Wmu,
                                                     const float* __restrict__ bmu,
                                                     const float* __restrict__ Wlv,
                                                     const float* __restrict__ blv,
                                                     float* __restrict__ out_mu,
                                                     float* __restrict__ out_lv, int n) {
  __shared__ _Float16 ylds_all[4][16 * YSTRIDE];
  const int wv = threadIdx.x >> 6;
  _Float16* ylds = ylds_all[wv];
  const int lane = threadIdx.x & 63;
  const int g = lane >> 3, q = lane & 7;
  const int quad = lane >> 4, col = lane & 15;

  half8 bfrag[2][4];
#pragma unroll
  for (int s = 0; s < 2; ++s)
#pragma unroll
    for (int t = 0; t < 4; ++t) {
      const int j = t * 16 + col;
      const float* W = (j < 32) ? Wmu : Wlv;
      const int jc = j & 31;
#pragma unroll
      for (int jj = 0; jj < 8; ++jj)
        bfrag[s][t][jj] = (_Float16)W[(s * 32 + quad * 8 + jj) * 32 + jc];
    }
  float bias[4];
#pragma unroll
  for (int t = 0; t < 4; ++t) {
    const int j = t * 16 + col;
    bias[t] = (j < 32) ? bmu[j] : blv[j - 32];
  }

  const int ntiles = (n + 15) >> 4;
  for (int tile = blockIdx.x * 4 + wv; tile < ntiles; tile += gridDim.x * 4) {
    const int row0 = tile << 4;
#pragma unroll 1
    for (int rg = 0; rg < 4; ++rg) {
      int start[4], end[4], idx[4];
      __half2 acc[4][4];
      int maxdeg = 0;
#pragma unroll
      for (int j = 0; j < 4; ++j) {
        const int i = row0 + rg * 4 + j;
        start[j] = 0; end[j] = 0;
        if (i < n) { start[j] = row_ptr[i]; end[j] = row_ptr[i + 1]; }
        maxdeg = imax(maxdeg, end[j] - start[j]);
#pragma unroll
        for (int k = 0; k < 4; ++k) acc[j][k] = u2h(0u);
        idx[j] = (start[j] + g < end[j]) ? pairs[start[j] + g] : n;
      }
      const int iters = (maxdeg + 7) >> 3;
#pragma unroll 1
      for (int it = 0; it < iters; ++it) {
        int nidx[4];
#pragma unroll
        for (int j = 0; j < 4; ++j) {
          const int ofs2 = start[j] + (it + 1) * 8 + g;
          nidx[j] = (ofs2 < end[j]) ? pairs[ofs2] : n;
        }
#pragma unroll
        for (int j = 0; j < 4; ++j) {
          const float4 rr = *(const float4*)(hsin + (size_t)idx[j] * 64 + q * 8);
          const __half2* hp = (const __half2*)&rr;
#pragma unroll
          for (int k = 0; k < 4; ++k) acc[j][k] = __hadd2(acc[j][k], hp[k]);
        }
#pragma unroll
        for (int j = 0; j < 4; ++j) idx[j] = nidx[j];
      }
#pragma unroll
      for (int j = 0; j < 4; ++j) {
        const int i = row0 + rg * 4 + j;
        if (g == 0 && i < n) {
          const float4 sr = *(const float4*)(hsin + (size_t)i * 64 + q * 8);
          const __half2* hp = (const __half2*)&sr;
#pragma unroll
          for (int k = 0; k < 4; ++k) acc[j][k] = __hadd2(acc[j][k], hp[k]);
        }
#pragma unroll
        for (int k = 0; k < 4; ++k) {
          unsigned u = __shfl_xor(h2u(acc[j][k]), 32);
          acc[j][k] = __hadd2(acc[j][k], u2h(u));
        }
        const float di = rsqrtf((float)(1 + end[j] - start[j]));
        const __half hdi = __float2half(di);
        const __half2 di2 = __halves2half2(hdi, hdi);
        uint4v st;
        st.x = h2u(__hmul2(di2, acc[j][0]));
        st.y = h2u(__hmul2(di2, acc[j][1]));
        st.z = h2u(__hmul2(di2, acc[j][2]));
        st.w = h2u(__hmul2(di2, acc[j][3]));
        *(uint4v*)(ylds + (rg * 4 + j) * YSTRIDE + (g & 3) * 64 + q * 8) = st;
      }
    }
    float4v acc[4];
#pragma unroll
    for (int t = 0; t < 4; ++t) acc[t] = (float4v){bias[t], bias[t], bias[t], bias[t]};
#pragma unroll
    for (int s2 = 0; s2 < 8; ++s2) {
      half8 af = *(half8*)(ylds + col * YSTRIDE + s2 * 32 + quad * 8);
      const int sW = s2 & 1;
#pragma unroll
      for (int t = 0; t < 4; ++t)
        acc[t] = __builtin_amdgcn_mfma_f32_16x16x32_f16(af, bfrag[sW][t], acc[t], 0, 0, 0);
    }
#pragma unroll
    for (int t = 0; t < 4; ++t)
#pragma unroll
      for (int reg = 0; reg < 4; ++reg) {
        const int row = row0 + quad * 4 + reg;
        if (row < n) {
          const int j = t * 16 + col;
          if (j < 32)
            out_mu[(size_t)row * 32 + j] = acc[t][reg];
          else
            out_lv[(size_t)row * 32 + (j - 32)] = acc[t][reg];
        }
      }
  }
}

extern "C" void kernel_launch(void* const* d_in, const int* in_sizes, int n_in,
                              void* d_out, int out_size, void* d_ws, size_t ws_size,
                              hipStream_t stream) {
  const float* x = (const float*)d_in[0];
  const int* ei = (const int*)d_in[1];  // [2, E] row-major int32
  const float* W1 = (const float*)d_in[2];
  const float* b1 = (const float*)d_in[3];
  const float* Wmu = (const float*)d_in[4];
  const float* bmu = (const float*)d_in[5];
  const float* Wlv = (const float*)d_in[6];
  const float* blv = (const float*)d_in[7];

  const int N = in_sizes[0] / 64;
  const int E = in_sizes[1] / 2;
  const int* src = ei;
  const int* dst = ei + E;

  const int NBK = (N + BKT_NODES - 1) >> BKT_SHIFT;  // 196 buckets (<=256)
  const int NBLK = (E + CHUNK - 1) / CHUNK;          // 391 chunks (<=512)
  const int FL = NBK * NBLK;                         // ~77k

  auto align256 = [](size_t v) { return (v + 255) & ~(size_t)255; };
  char* p = (char*)d_ws;
  int* row_ptr = (int*)p;  p += align256((size_t)(N + 1) * 4);
  float* dinv = (float*)p; p += align256((size_t)N * 4);
  int* rowsum = (int*)p;   p += align256((size_t)256 * 4);
  int* cnt = (int*)p;      p += align256((size_t)FL * 4);
  int* pairs = (int*)p;    p += align256((size_t)E * 4);
  __half* xs = (__half*)p; p += align256((size_t)(N + 1) * 64 * 2);
  size_t tmp_bytes = (size_t)E * 4;  // packed int
  size_t hs_bytes = (size_t)(N + 1) * 64 * 2;
  int* tmp = (int*)p;      // union: tmp dead after bucket_build; hs written later
  __half* hs = (__half*)p;
  p += align256(tmp_bytes > hs_bytes ? tmp_bytes : hs_bytes);

  float* out_mu = (float*)d_out;
  float* out_lv = out_mu + (size_t)N * 32;

  const int n4 = N * 16;

  // --- CSR build: 4 plain dispatches, single-pass LDS-staged kernels ---
  bucket_count<<<NBLK, 512, 0, stream>>>(dst, cnt, E, NBK, NBLK);
  scan_rows<<<NBK, 256, 0, stream>>>(cnt, rowsum, NBK, NBLK);
  bucket_scatter<<<NBLK, 512, 0, stream>>>(src, dst, cnt, rowsum, tmp, E, NBK, NBLK);
  bucket_build<<<NBK, 1024, 0, stream>>>(tmp, rowsum, row_ptr, dinv, pairs, N, NBK, E);

  // --- tables (chip-filling standalone cast; after build, hs aliases tmp) ---
  cast_scale<<<(n4 + 32 + 255) / 256, 256, 0, stream>>>(x, dinv, xs, hs, n4, N);

  // --- aggregation + fused dense layers (MFMA epilogue) ---
  const int ntiles = (N + 15) / 16;
  const int ablocks = (ntiles + 3) / 4;  // 1 tile (16 rows) per wave
  agg_layer1<<<ablocks, 256, 0, stream>>>(xs, pairs, row_ptr, W1, b1, hs, N);
  agg_layer2<<<ablocks, 256, 0, stream>>>(hs, pairs, row_ptr, Wmu, bmu, Wlv, blv,
                                          out_mu, out_lv, N);
}